// Round 4
// baseline (3500.087 us; speedup 1.0000x reference)
//
#include <hip/hip_runtime.h>
#include <math.h>

// FAVOR+ linear attention (Performer), fp32, MI355X. b=4 n=4096 h=8 d=64 m=256.
// R4: occupancy/latency rewrite.
//   k_init, k_diag unchanged.
//   k_proj<false>: LDS-staged tile; stores e2 = exp(dd2 - diag2) (stab factored out:
//                  exp(dd-diag-stab) == e2 * exp(-stab)); tracks per-bh max(dd2) -> atomicMaxF.
//   k_proj<true> : LDS-staged tile; fused per-position max + exp -> final v1p.
//   k_v2accum    : 2048 blocks (bh x 4 m-quarters x 16 n-chunks); finalizes v2p =
//                  ratio*(e2*s + eps) in place; accumulates exclusive per-block partials
//                  of v2x/v2sum (no atomics) if ws fits, else atomic fallback.
//   k_reduce     : folds 16 chunk-partials -> v2x[bh][m][d], v2sum[bh][m].
//   k_pv         : out = (v1p @ v2x) / (v1p . v2sum); 4 m-phases, 35.6KB LDS (4 blk/CU).

namespace {
constexpr int B_ = 4, N_ = 4096, H_ = 8, D_ = 64, M_ = 256;
constexpr int BH_ = B_ * H_;          // 32
constexpr int POS_ = B_ * N_ * H_;    // 131072
constexpr float SCALE_ = 0.35355339059327378f;  // 64^-0.25 (tau=1)
constexpr float RATIO_ = 0.0625f;               // 256^-0.5
constexpr float FEPS_ = 1e-6f;

// ws layout (float offsets)
constexpr int WS_BHMAX = 0;                       // 32 floats, init -inf
constexpr int WS_V2X   = 32;                      // 32*256*64 = 524288
constexpr int WS_V2SUM = WS_V2X + BH_ * M_ * D_;  // 524320, 8192 floats
constexpr int WS_DIAG1 = WS_V2SUM + BH_ * M_;     // 532512
constexpr int WS_DIAG2 = WS_DIAG1 + POS_;         // 663584
constexpr int WS_PART  = WS_DIAG2 + POS_;         // 794656; 16*32*4*4096 = 8388608 floats
constexpr int WS_PSUM  = WS_PART + 16 * 32 * 4 * 4096;   // 9183264; 16*32*4*64 = 131072
constexpr int WS_END   = WS_PSUM + 16 * 32 * 4 * 64;     // 9314336 floats
constexpr int WS_ZERO_END = WS_DIAG1;             // [32, WS_DIAG1) zeroed (atomic fallback)
}

__device__ __forceinline__ void atomicMaxF(float* addr, float v) {
  // ordered-int trick; works given init = -inf
  if (v >= 0.f)
    atomicMax((int*)addr, __float_as_int(v));
  else
    atomicMin((unsigned int*)addr, __float_as_uint(v));
}

// ---------------------------------------------------------------- init
__global__ void k_init(float* __restrict__ ws) {
  int i = blockIdx.x * 256 + threadIdx.x;
  int stride = gridDim.x * 256;
  for (; i < WS_ZERO_END; i += stride) {
    ws[i] = (i < 32) ? -INFINITY : 0.f;
  }
}

// ---------------------------------------------------------------- diag
// 64 rows per block, 4 threads per row (16 floats each)
__global__ void k_diag(const float* __restrict__ v1, const float* __restrict__ v2,
                       float* __restrict__ ws) {
  int t = threadIdx.x;
  int r = t >> 2, seg = t & 3;
  int rowg = blockIdx.x * 64 + r;  // 0 .. 2*POS-1
  const float* src;
  float* dst;
  int row;
  if (rowg < POS_) { src = v1; dst = ws + WS_DIAG1; row = rowg; }
  else             { src = v2; dst = ws + WS_DIAG2; row = rowg - POS_; }
  const float4* p = reinterpret_cast<const float4*>(src + (size_t)row * 64) + seg * 4;
  float s = 0.f;
#pragma unroll
  for (int j = 0; j < 4; ++j) {
    float4 v = p[j];
    s = fmaf(v.x, v.x, s); s = fmaf(v.y, v.y, s);
    s = fmaf(v.z, v.z, s); s = fmaf(v.w, v.w, s);
  }
  s += __shfl_xor(s, 1);
  s += __shfl_xor(s, 2);
  if (seg == 0) dst[row] = 0.0625f * s;  // 0.5 * SCALE^2 * sum
}

// ---------------------------------------------------------------- projection
// 1024 blocks = bh(32) x tile(32); 128 n per block; 256 threads, thread t owns m=t.
// Data tile staged in LDS (32KB, broadcast reads); pr[] pre-scaled in 64 VGPRs.
// IS_QUERY: per-position max + exp -> final v1p. else: e2 = exp(dd - diag2) + bh max(dd).
template <bool IS_QUERY>
__global__ __launch_bounds__(256, 4) void k_proj(const float* __restrict__ vec,
                                                 const float* __restrict__ Pm,
                                                 float* __restrict__ ddout,
                                                 float* __restrict__ ws) {
  __shared__ float4 sD[128 * 16];  // [row][fq], 32 KB; reads are wave-uniform (broadcast)
  __shared__ float wmax[2][4][8];
  __shared__ float wm[4];
  int t = threadIdx.x;
  int bh = blockIdx.x >> 5, tile = blockIdx.x & 31;
  int b = bh >> 3, h = bh & 7;

  float4 pr[16];
  {
    const float4* pp = reinterpret_cast<const float4*>(Pm + t * 64);
#pragma unroll
    for (int j = 0; j < 16; ++j) {
      float4 v = pp[j];
      pr[j].x = v.x * SCALE_; pr[j].y = v.y * SCALE_;
      pr[j].z = v.z * SCALE_; pr[j].w = v.w * SCALE_;
    }
  }

  // stage 128 rows x 64 floats (row stride in global = H*64 = 512 floats)
  {
    const float* base = vec + ((size_t)(b * N_ + tile * 128) * H_ + h) * 64;
    int r0 = t >> 4, fq = t & 15;
#pragma unroll
    for (int i = 0; i < 8; ++i) {
      int row = i * 16 + r0;
      sD[row * 16 + fq] =
          *reinterpret_cast<const float4*>(base + (size_t)row * 512 + fq * 4);
    }
  }
  __syncthreads();

  int wv = t >> 6, ln = t & 63;
  const float* diag = ws + (IS_QUERY ? WS_DIAG1 : WS_DIAG2);
  int pgbase = (b * N_ + tile * 128) * H_ + h;
  float vmaxk = -INFINITY;

  for (int grp = 0; grp < 16; ++grp) {
    float a[8];
#pragma unroll
    for (int cp = 0; cp < 8; ++cp) {
      const float4* rp = &sD[(grp * 8 + cp) * 16];
      float acc = 0.f;
#pragma unroll
      for (int j = 0; j < 16; ++j) {
        float4 dv = rp[j];
        acc = fmaf(dv.x, pr[j].x, acc);
        acc = fmaf(dv.y, pr[j].y, acc);
        acc = fmaf(dv.z, pr[j].z, acc);
        acc = fmaf(dv.w, pr[j].w, acc);
      }
      a[cp] = acc;
    }
    if (IS_QUERY) {
      int buf = grp & 1;
#pragma unroll
      for (int cp = 0; cp < 8; ++cp) {
        float m = a[cp];
#pragma unroll
        for (int o = 1; o < 64; o <<= 1) m = fmaxf(m, __shfl_xor(m, o));
        if (ln == 0) wmax[buf][wv][cp] = m;
      }
      __syncthreads();
#pragma unroll
      for (int cp = 0; cp < 8; ++cp) {
        int pg = pgbase + (grp * 8 + cp) * H_;
        float mx = fmaxf(fmaxf(wmax[buf][0][cp], wmax[buf][1][cp]),
                         fmaxf(wmax[buf][2][cp], wmax[buf][3][cp]));
        ddout[(size_t)pg * M_ + t] = RATIO_ * (__expf(a[cp] - diag[pg] - mx) + FEPS_);
      }
    } else {
#pragma unroll
      for (int cp = 0; cp < 8; ++cp) {
        int pg = pgbase + (grp * 8 + cp) * H_;
        vmaxk = fmaxf(vmaxk, a[cp]);
        ddout[(size_t)pg * M_ + t] = __expf(a[cp] - diag[pg]);  // e2, stab factored out
      }
    }
  }
  if (!IS_QUERY) {
#pragma unroll
    for (int o = 1; o < 64; o <<= 1) vmaxk = fmaxf(vmaxk, __shfl_xor(vmaxk, o));
    if (ln == 0) wm[wv] = vmaxk;
    __syncthreads();
    if (t == 0)
      atomicMaxF(ws + WS_BHMAX + bh, fmaxf(fmaxf(wm[0], wm[1]), fmaxf(wm[2], wm[3])));
  }
}

// ---------------------------------------------------------------- v2 finalize + accumulate
// 2048 blocks = bh(32) x mq(4, 64-m quarter) x chunk(16, 256 n). 16 sub-iters x 16 n.
// thread: mg=t>>3 owns 2 m; dgi=t&7 owns 8 d; acc[2][8]. LDS 8.7KB -> high occupancy.
// use_part: exclusive partial buffers (no atomics); else atomicAdd fallback.
__global__ __launch_bounds__(256) void k_v2accum(const float* __restrict__ x,
                                                 float* __restrict__ v2p,  // in: e2, out: v2p
                                                 float* __restrict__ ws, int use_part) {
  __shared__ float sE[16][68];
  __shared__ float sX[16][68];
  int t = threadIdx.x;
  int bx = blockIdx.x;
  int chunk = bx & 15, mq = (bx >> 4) & 3, bh = bx >> 6;
  int b = bh >> 3, h = bh & 7;
  int n0 = chunk * 256;
  float rs = RATIO_ * __expf(-ws[WS_BHMAX + bh]);  // v2p = e2*rs + re
  float re = RATIO_ * FEPS_;

  int mg = t >> 3, dgi = t & 7;
  int r0 = t >> 4, fq = t & 15;

  float acc[2][8];
  float acc2[2] = {0.f, 0.f};
#pragma unroll
  for (int i = 0; i < 2; ++i)
#pragma unroll
    for (int j = 0; j < 8; ++j) acc[i][j] = 0.f;

  for (int it = 0; it < 16; ++it) {
    __syncthreads();
    {
      size_t pg = (size_t)(b * N_ + n0 + it * 16 + r0) * H_ + h;
      float* gp = v2p + pg * M_ + mq * 64 + fq * 4;
      float4 ev = *reinterpret_cast<const float4*>(gp);
      float4 vv;
      vv.x = fmaf(ev.x, rs, re); vv.y = fmaf(ev.y, rs, re);
      vv.z = fmaf(ev.z, rs, re); vv.w = fmaf(ev.w, rs, re);
      *reinterpret_cast<float4*>(gp) = vv;
      *reinterpret_cast<float4*>(&sE[r0][fq * 4]) = vv;
      float4 xv = *reinterpret_cast<const float4*>(x + pg * 64 + fq * 4);
      *reinterpret_cast<float4*>(&sX[r0][fq * 4]) = xv;
    }
    __syncthreads();
#pragma unroll 4
    for (int nn = 0; nn < 16; ++nn) {
      float2 ev = *reinterpret_cast<const float2*>(&sE[nn][mg * 2]);
      float4 b0 = *reinterpret_cast<const float4*>(&sX[nn][dgi * 8]);
      float4 b1 = *reinterpret_cast<const float4*>(&sX[nn][dgi * 8 + 4]);
      acc2[0] += ev.x; acc2[1] += ev.y;
      acc[0][0] = fmaf(ev.x, b0.x, acc[0][0]); acc[0][1] = fmaf(ev.x, b0.y, acc[0][1]);
      acc[0][2] = fmaf(ev.x, b0.z, acc[0][2]); acc[0][3] = fmaf(ev.x, b0.w, acc[0][3]);
      acc[0][4] = fmaf(ev.x, b1.x, acc[0][4]); acc[0][5] = fmaf(ev.x, b1.y, acc[0][5]);
      acc[0][6] = fmaf(ev.x, b1.z, acc[0][6]); acc[0][7] = fmaf(ev.x, b1.w, acc[0][7]);
      acc[1][0] = fmaf(ev.y, b0.x, acc[1][0]); acc[1][1] = fmaf(ev.y, b0.y, acc[1][1]);
      acc[1][2] = fmaf(ev.y, b0.z, acc[1][2]); acc[1][3] = fmaf(ev.y, b0.w, acc[1][3]);
      acc[1][4] = fmaf(ev.y, b1.x, acc[1][4]); acc[1][5] = fmaf(ev.y, b1.y, acc[1][5]);
      acc[1][6] = fmaf(ev.y, b1.z, acc[1][6]); acc[1][7] = fmaf(ev.y, b1.w, acc[1][7]);
    }
  }

  if (use_part) {
    float* pp = ws + WS_PART + (((size_t)chunk * BH_ + bh) * 4 + mq) * 4096;
#pragma unroll
    for (int i = 0; i < 2; ++i) {
      float* q = pp + (mg * 2 + i) * 64 + dgi * 8;
      *reinterpret_cast<float4*>(q)     = make_float4(acc[i][0], acc[i][1], acc[i][2], acc[i][3]);
      *reinterpret_cast<float4*>(q + 4) = make_float4(acc[i][4], acc[i][5], acc[i][6], acc[i][7]);
    }
    if (dgi == 0) {
      float* ps = ws + WS_PSUM + (((size_t)chunk * BH_ + bh) * 4 + mq) * 64 + mg * 2;
      ps[0] = acc2[0]; ps[1] = acc2[1];
    }
  } else {
    float* vx = ws + WS_V2X + (size_t)bh * M_ * D_;
#pragma unroll
    for (int i = 0; i < 2; ++i)
#pragma unroll
      for (int j = 0; j < 8; ++j)
        atomicAdd(vx + (mq * 64 + mg * 2 + i) * 64 + dgi * 8 + j, acc[i][j]);
    if (dgi == 0) {
      float* vs = ws + WS_V2SUM + (size_t)bh * M_;
#pragma unroll
      for (int i = 0; i < 2; ++i) atomicAdd(vs + mq * 64 + mg * 2 + i, acc2[i]);
    }
  }
}

// ---------------------------------------------------------------- partial reduce
// 544 blocks x 256: first 131072 threads fold v2x float4s, next 8192 fold v2sum.
__global__ void k_reduce(float* __restrict__ ws) {
  int i = blockIdx.x * 256 + threadIdx.x;
  if (i < 131072) {  // float4 index over [bh][m][d/4]
    int bh = i >> 12, rem = i & 4095;
    int m = rem >> 4, dq = rem & 15;
    int mq = m >> 6, mloc = m & 63;
    float4 s = make_float4(0.f, 0.f, 0.f, 0.f);
#pragma unroll
    for (int c = 0; c < 16; ++c) {
      const float4 v = *reinterpret_cast<const float4*>(
          ws + WS_PART + (((size_t)c * BH_ + bh) * 4 + mq) * 4096 + mloc * 64 + dq * 4);
      s.x += v.x; s.y += v.y; s.z += v.z; s.w += v.w;
    }
    *reinterpret_cast<float4*>(ws + WS_V2X + (size_t)i * 4) = s;
  } else if (i < 131072 + 8192) {
    int j = i - 131072;
    int bh = j >> 8, m = j & 255;
    int mq = m >> 6, mloc = m & 63;
    float s = 0.f;
#pragma unroll
    for (int c = 0; c < 16; ++c)
      s += ws[WS_PSUM + (((size_t)c * BH_ + bh) * 4 + mq) * 64 + mloc];
    ws[WS_V2SUM + j] = s;
  }
}

// ---------------------------------------------------------------- PV + out
// 2048 blocks = bh(32) x tile(64 pos). thread (pg_=t&15, dg=t>>4) owns 4 pos x 4 d.
// 4 m-phases of 64: sA 64x67 (17.2K, 2-way-free reads) + sB 64x68 (17.4K) -> 4 blk/CU.
__global__ __launch_bounds__(256) void k_pv(const float* __restrict__ v1p,
                                            float* __restrict__ ws,
                                            float* __restrict__ out) {
  __shared__ float sA[64][67];
  __shared__ float sB[64][68];
  __shared__ float sVs[256];
  int t = threadIdx.x;
  int bh = blockIdx.x >> 6, tile = blockIdx.x & 63;
  int b = bh >> 3, h = bh & 7;
  int pg_ = t & 15, dg = t >> 4;
  int pl = t >> 2, ps = t & 3;

  if (t < 64) {
    float4 v = *reinterpret_cast<const float4*>(ws + WS_V2SUM + bh * M_ + t * 4);
    *reinterpret_cast<float4*>(&sVs[t * 4]) = v;
  }

  float acc1[4][4];
  float acc2[4];
#pragma unroll
  for (int i = 0; i < 4; ++i) {
    acc2[i] = 0.f;
#pragma unroll
    for (int j = 0; j < 4; ++j) acc1[i][j] = 0.f;
  }

  size_t posg_base = (size_t)(b * N_ + tile * 64) * H_ + h;

  for (int ph = 0; ph < 4; ++ph) {
    __syncthreads();
    int m0 = ph * 64;
    {
      const float* gp = v1p + (posg_base + (size_t)pl * H_) * M_ + m0;
#pragma unroll
      for (int j = 0; j < 4; ++j) {
        int mcol = ps * 4 + j * 16;
        float4 v = *reinterpret_cast<const float4*>(gp + mcol);
        sA[pl][mcol] = v.x; sA[pl][mcol + 1] = v.y;
        sA[pl][mcol + 2] = v.z; sA[pl][mcol + 3] = v.w;
      }
      const float* gb = ws + WS_V2X + (size_t)bh * M_ * D_ + (size_t)(m0 + pl) * 64 + ps * 16;
#pragma unroll
      for (int j = 0; j < 4; ++j) {
        float4 v = *reinterpret_cast<const float4*>(gb + j * 4);
        *reinterpret_cast<float4*>(&sB[pl][ps * 16 + j * 4]) = v;
      }
    }
    __syncthreads();
#pragma unroll 4
    for (int m = 0; m < 64; ++m) {
      float a0 = sA[4 * pg_ + 0][m];
      float a1 = sA[4 * pg_ + 1][m];
      float a2 = sA[4 * pg_ + 2][m];
      float a3 = sA[4 * pg_ + 3][m];
      float4 bv = *reinterpret_cast<const float4*>(&sB[m][dg * 4]);
      float vsm = sVs[m0 + m];
      acc1[0][0] = fmaf(a0, bv.x, acc1[0][0]); acc1[0][1] = fmaf(a0, bv.y, acc1[0][1]);
      acc1[0][2] = fmaf(a0, bv.z, acc1[0][2]); acc1[0][3] = fmaf(a0, bv.w, acc1[0][3]);
      acc1[1][0] = fmaf(a1, bv.x, acc1[1][0]); acc1[1][1] = fmaf(a1, bv.y, acc1[1][1]);
      acc1[1][2] = fmaf(a1, bv.z, acc1[1][2]); acc1[1][3] = fmaf(a1, bv.w, acc1[1][3]);
      acc1[2][0] = fmaf(a2, bv.x, acc1[2][0]); acc1[2][1] = fmaf(a2, bv.y, acc1[2][1]);
      acc1[2][2] = fmaf(a2, bv.z, acc1[2][2]); acc1[2][3] = fmaf(a2, bv.w, acc1[2][3]);
      acc1[3][0] = fmaf(a3, bv.x, acc1[3][0]); acc1[3][1] = fmaf(a3, bv.y, acc1[3][1]);
      acc1[3][2] = fmaf(a3, bv.z, acc1[3][2]); acc1[3][3] = fmaf(a3, bv.w, acc1[3][3]);
      acc2[0] = fmaf(a0, vsm, acc2[0]);
      acc2[1] = fmaf(a1, vsm, acc2[1]);
      acc2[2] = fmaf(a2, vsm, acc2[2]);
      acc2[3] = fmaf(a3, vsm, acc2[3]);
    }
  }

#pragma unroll
  for (int i = 0; i < 4; ++i) {
    size_t pg = posg_base + (size_t)(4 * pg_ + i) * H_;
    float inv = 1.f / acc2[i];
    float4 o;
    o.x = acc1[i][0] * inv; o.y = acc1[i][1] * inv;
    o.z = acc1[i][2] * inv; o.w = acc1[i][3] * inv;
    *reinterpret_cast<float4*>(out + pg * 64 + dg * 4) = o;
  }
}

// ---------------------------------------------------------------- launch
extern "C" void kernel_launch(void* const* d_in, const int* in_sizes, int n_in,
                              void* d_out, int out_size, void* d_ws, size_t ws_size,
                              hipStream_t stream) {
  const float* x  = (const float*)d_in[0];
  const float* v1 = (const float*)d_in[1];
  const float* v2 = (const float*)d_in[2];
  const float* Pm = (const float*)d_in[3];
  float* out = (float*)d_out;
  float* v1p = out + (size_t)POS_ * D_;           // 8388608
  float* v2p = v1p + (size_t)POS_ * M_;           // 41943040
  float* ws = (float*)d_ws;
  int use_part = (ws_size >= (size_t)WS_END * 4) ? 1 : 0;

  k_init<<<1024, 256, 0, stream>>>(ws);
  k_diag<<<2 * POS_ / 64, 256, 0, stream>>>(v1, v2, ws);
  k_proj<false><<<BH_ * 32, 256, 0, stream>>>(v2, Pm, v2p, ws);  // e2 + bh max
  k_proj<true><<<BH_ * 32, 256, 0, stream>>>(v1, Pm, v1p, ws);   // final v1p
  k_v2accum<<<2048, 256, 0, stream>>>(x, v2p, ws, use_part);     // v2p + partials
  if (use_part) k_reduce<<<544, 256, 0, stream>>>(ws);           // -> v2x, v2sum
  k_pv<<<2048, 256, 0, stream>>>(v1p, ws, out);                  // out
}

// Round 7
// 903.815 us; speedup vs baseline: 3.8726x; 3.8726x over previous
//
#include <hip/hip_runtime.h>
#include <math.h>

// FAVOR+ linear attention (Performer), fp32, MI355X. b=4 n=4096 h=8 d=64 m=256.
// R5: un-spill k_proj (plain launch_bounds; R4's ",4" forced VGPR=64 -> 9.4GB scratch
//     thrash per dispatch) + fuse diag computation into k_proj (k_diag removed).
//   k_proj<false>: LDS tile + in-block diag; stores e2 = exp(dd2 - diag2); per-bh max(dd2).
//   k_proj<true> : LDS tile + in-block diag; fused per-position max + exp -> final v1p.
//   k_v2accum    : finalizes v2p = e2*rs + re in place; exclusive per-block partials.
//   k_reduce     : folds 16 chunk-partials -> v2x, v2sum.
//   k_pv         : out = (v1p @ v2x) / (v1p . v2sum).

namespace {
constexpr int B_ = 4, N_ = 4096, H_ = 8, D_ = 64, M_ = 256;
constexpr int BH_ = B_ * H_;          // 32
constexpr int POS_ = B_ * N_ * H_;    // 131072
constexpr float SCALE_ = 0.35355339059327378f;  // 64^-0.25 (tau=1)
constexpr float RATIO_ = 0.0625f;               // 256^-0.5
constexpr float FEPS_ = 1e-6f;

// ws layout (float offsets)
constexpr int WS_BHMAX = 0;                       // 32 floats, init -inf
constexpr int WS_V2X   = 32;                      // 32*256*64 = 524288
constexpr int WS_V2SUM = WS_V2X + BH_ * M_ * D_;  // 524320, 8192 floats
constexpr int WS_DIAG1 = WS_V2SUM + BH_ * M_;     // (diag regions now unused; kept for layout)
constexpr int WS_DIAG2 = WS_DIAG1 + POS_;
constexpr int WS_PART  = WS_DIAG2 + POS_;         // 16*32*4*4096 = 8388608 floats
constexpr int WS_PSUM  = WS_PART + 16 * 32 * 4 * 4096;
constexpr int WS_END   = WS_PSUM + 16 * 32 * 4 * 64;
constexpr int WS_ZERO_END = WS_DIAG1;             // [32, WS_DIAG1) zeroed (atomic fallback)
}

__device__ __forceinline__ void atomicMaxF(float* addr, float v) {
  // ordered-int trick; works given init = -inf
  if (v >= 0.f)
    atomicMax((int*)addr, __float_as_int(v));
  else
    atomicMin((unsigned int*)addr, __float_as_uint(v));
}

// ---------------------------------------------------------------- init
__global__ void k_init(float* __restrict__ ws) {
  int i = blockIdx.x * 256 + threadIdx.x;
  int stride = gridDim.x * 256;
  for (; i < WS_ZERO_END; i += stride) {
    ws[i] = (i < 32) ? -INFINITY : 0.f;
  }
}

// ---------------------------------------------------------------- projection (+fused diag)
// 1024 blocks = bh(32) x tile(32); 128 n per block; 256 threads, thread t owns m=t.
// Data tile staged in LDS (32KB, broadcast reads); pr[] pre-scaled in 64 VGPRs.
// NOTE: no min-waves in launch_bounds — R4's ",4" capped VGPR at 64 and spilled pr[] to
// scratch (9.4GB HBM traffic/dispatch). Natural allocation ~100 VGPR, no spill.
template <bool IS_QUERY>
__global__ __launch_bounds__(256) void k_proj(const float* __restrict__ vec,
                                              const float* __restrict__ Pm,
                                              float* __restrict__ ddout,
                                              float* __restrict__ ws) {
  __shared__ float4 sD[128 * 16];  // [row][fq], 32 KB; reads are wave-uniform (broadcast)
  __shared__ float sDiag[128];
  __shared__ float wmax[2][4][8];
  __shared__ float wm[4];
  int t = threadIdx.x;
  int bh = blockIdx.x >> 5, tile = blockIdx.x & 31;
  int b = bh >> 3, h = bh & 7;

  float4 pr[16];
  {
    const float4* pp = reinterpret_cast<const float4*>(Pm + t * 64);
#pragma unroll
    for (int j = 0; j < 16; ++j) {
      float4 v = pp[j];
      pr[j].x = v.x * SCALE_; pr[j].y = v.y * SCALE_;
      pr[j].z = v.z * SCALE_; pr[j].w = v.w * SCALE_;
    }
  }

  // stage 128 rows x 64 floats (row stride in global = H*64 = 512 floats)
  {
    const float* base = vec + ((size_t)(b * N_ + tile * 128) * H_ + h) * 64;
    int r0 = t >> 4, fq = t & 15;
#pragma unroll
    for (int i = 0; i < 8; ++i) {
      int row = i * 16 + r0;
      sD[row * 16 + fq] =
          *reinterpret_cast<const float4*>(base + (size_t)row * 512 + fq * 4);
    }
  }
  __syncthreads();

  // fused diag: thread t sums squares of half a row; pair-combine via shfl.
  {
    int r = t >> 1, hf = t & 1;
    const float4* rp = &sD[r * 16 + hf * 8];
    float s = 0.f;
#pragma unroll
    for (int j = 0; j < 8; ++j) {
      float4 v = rp[j];
      s = fmaf(v.x, v.x, s); s = fmaf(v.y, v.y, s);
      s = fmaf(v.z, v.z, s); s = fmaf(v.w, v.w, s);
    }
    s += __shfl_xor(s, 1);
    if (hf == 0) sDiag[r] = 0.0625f * s;  // 0.5 * SCALE^2 * sum(raw^2)
  }
  __syncthreads();

  int wv = t >> 6, ln = t & 63;
  int pgbase = (b * N_ + tile * 128) * H_ + h;
  float vmaxk = -INFINITY;

  for (int grp = 0; grp < 16; ++grp) {
    float a[8];
#pragma unroll
    for (int cp = 0; cp < 8; ++cp) {
      const float4* rp = &sD[(grp * 8 + cp) * 16];
      float acc = 0.f;
#pragma unroll
      for (int j = 0; j < 16; ++j) {
        float4 dv = rp[j];
        acc = fmaf(dv.x, pr[j].x, acc);
        acc = fmaf(dv.y, pr[j].y, acc);
        acc = fmaf(dv.z, pr[j].z, acc);
        acc = fmaf(dv.w, pr[j].w, acc);
      }
      a[cp] = acc;
    }
    if (IS_QUERY) {
      int buf = grp & 1;
#pragma unroll
      for (int cp = 0; cp < 8; ++cp) {
        float m = a[cp];
#pragma unroll
        for (int o = 1; o < 64; o <<= 1) m = fmaxf(m, __shfl_xor(m, o));
        if (ln == 0) wmax[buf][wv][cp] = m;
      }
      __syncthreads();
#pragma unroll
      for (int cp = 0; cp < 8; ++cp) {
        int pg = pgbase + (grp * 8 + cp) * H_;
        float mx = fmaxf(fmaxf(wmax[buf][0][cp], wmax[buf][1][cp]),
                         fmaxf(wmax[buf][2][cp], wmax[buf][3][cp]));
        ddout[(size_t)pg * M_ + t] =
            RATIO_ * (__expf(a[cp] - sDiag[grp * 8 + cp] - mx) + FEPS_);
      }
    } else {
#pragma unroll
      for (int cp = 0; cp < 8; ++cp) {
        int pg = pgbase + (grp * 8 + cp) * H_;
        vmaxk = fmaxf(vmaxk, a[cp]);
        ddout[(size_t)pg * M_ + t] = __expf(a[cp] - sDiag[grp * 8 + cp]);  // e2
      }
    }
  }
  if (!IS_QUERY) {
#pragma unroll
    for (int o = 1; o < 64; o <<= 1) vmaxk = fmaxf(vmaxk, __shfl_xor(vmaxk, o));
    if (ln == 0) wm[wv] = vmaxk;
    __syncthreads();
    if (t == 0)
      atomicMaxF(ws + WS_BHMAX + bh, fmaxf(fmaxf(wm[0], wm[1]), fmaxf(wm[2], wm[3])));
  }
}

// ---------------------------------------------------------------- v2 finalize + accumulate
// 2048 blocks = bh(32) x mq(4, 64-m quarter) x chunk(16, 256 n). 16 sub-iters x 16 n.
// thread: mg=t>>3 owns 2 m; dgi=t&7 owns 8 d; acc[2][8]. LDS 8.7KB -> high occupancy.
// use_part: exclusive partial buffers (no atomics); else atomicAdd fallback.
__global__ __launch_bounds__(256) void k_v2accum(const float* __restrict__ x,
                                                 float* __restrict__ v2p,  // in: e2, out: v2p
                                                 float* __restrict__ ws, int use_part) {
  __shared__ float sE[16][68];
  __shared__ float sX[16][68];
  int t = threadIdx.x;
  int bx = blockIdx.x;
  int chunk = bx & 15, mq = (bx >> 4) & 3, bh = bx >> 6;
  int b = bh >> 3, h = bh & 7;
  int n0 = chunk * 256;
  float rs = RATIO_ * __expf(-ws[WS_BHMAX + bh]);  // v2p = e2*rs + re
  float re = RATIO_ * FEPS_;

  int mg = t >> 3, dgi = t & 7;
  int r0 = t >> 4, fq = t & 15;

  float acc[2][8];
  float acc2[2] = {0.f, 0.f};
#pragma unroll
  for (int i = 0; i < 2; ++i)
#pragma unroll
    for (int j = 0; j < 8; ++j) acc[i][j] = 0.f;

  for (int it = 0; it < 16; ++it) {
    __syncthreads();
    {
      size_t pg = (size_t)(b * N_ + n0 + it * 16 + r0) * H_ + h;
      float* gp = v2p + pg * M_ + mq * 64 + fq * 4;
      float4 ev = *reinterpret_cast<const float4*>(gp);
      float4 vv;
      vv.x = fmaf(ev.x, rs, re); vv.y = fmaf(ev.y, rs, re);
      vv.z = fmaf(ev.z, rs, re); vv.w = fmaf(ev.w, rs, re);
      *reinterpret_cast<float4*>(gp) = vv;
      *reinterpret_cast<float4*>(&sE[r0][fq * 4]) = vv;
      float4 xv = *reinterpret_cast<const float4*>(x + pg * 64 + fq * 4);
      *reinterpret_cast<float4*>(&sX[r0][fq * 4]) = xv;
    }
    __syncthreads();
#pragma unroll 4
    for (int nn = 0; nn < 16; ++nn) {
      float2 ev = *reinterpret_cast<const float2*>(&sE[nn][mg * 2]);
      float4 b0 = *reinterpret_cast<const float4*>(&sX[nn][dgi * 8]);
      float4 b1 = *reinterpret_cast<const float4*>(&sX[nn][dgi * 8 + 4]);
      acc2[0] += ev.x; acc2[1] += ev.y;
      acc[0][0] = fmaf(ev.x, b0.x, acc[0][0]); acc[0][1] = fmaf(ev.x, b0.y, acc[0][1]);
      acc[0][2] = fmaf(ev.x, b0.z, acc[0][2]); acc[0][3] = fmaf(ev.x, b0.w, acc[0][3]);
      acc[0][4] = fmaf(ev.x, b1.x, acc[0][4]); acc[0][5] = fmaf(ev.x, b1.y, acc[0][5]);
      acc[0][6] = fmaf(ev.x, b1.z, acc[0][6]); acc[0][7] = fmaf(ev.x, b1.w, acc[0][7]);
      acc[1][0] = fmaf(ev.y, b0.x, acc[1][0]); acc[1][1] = fmaf(ev.y, b0.y, acc[1][1]);
      acc[1][2] = fmaf(ev.y, b0.z, acc[1][2]); acc[1][3] = fmaf(ev.y, b0.w, acc[1][3]);
      acc[1][4] = fmaf(ev.y, b1.x, acc[1][4]); acc[1][5] = fmaf(ev.y, b1.y, acc[1][5]);
      acc[1][6] = fmaf(ev.y, b1.z, acc[1][6]); acc[1][7] = fmaf(ev.y, b1.w, acc[1][7]);
    }
  }

  if (use_part) {
    float* pp = ws + WS_PART + (((size_t)chunk * BH_ + bh) * 4 + mq) * 4096;
#pragma unroll
    for (int i = 0; i < 2; ++i) {
      float* q = pp + (mg * 2 + i) * 64 + dgi * 8;
      *reinterpret_cast<float4*>(q)     = make_float4(acc[i][0], acc[i][1], acc[i][2], acc[i][3]);
      *reinterpret_cast<float4*>(q + 4) = make_float4(acc[i][4], acc[i][5], acc[i][6], acc[i][7]);
    }
    if (dgi == 0) {
      float* ps = ws + WS_PSUM + (((size_t)chunk * BH_ + bh) * 4 + mq) * 64 + mg * 2;
      ps[0] = acc2[0]; ps[1] = acc2[1];
    }
  } else {
    float* vx = ws + WS_V2X + (size_t)bh * M_ * D_;
#pragma unroll
    for (int i = 0; i < 2; ++i)
#pragma unroll
      for (int j = 0; j < 8; ++j)
        atomicAdd(vx + (mq * 64 + mg * 2 + i) * 64 + dgi * 8 + j, acc[i][j]);
    if (dgi == 0) {
      float* vs = ws + WS_V2SUM + (size_t)bh * M_;
#pragma unroll
      for (int i = 0; i < 2; ++i) atomicAdd(vs + mq * 64 + mg * 2 + i, acc2[i]);
    }
  }
}

// ---------------------------------------------------------------- partial reduce
// 544 blocks x 256: first 131072 threads fold v2x float4s, next 8192 fold v2sum.
__global__ void k_reduce(float* __restrict__ ws) {
  int i = blockIdx.x * 256 + threadIdx.x;
  if (i < 131072) {  // float4 index over [bh][m][d/4]
    int bh = i >> 12, rem = i & 4095;
    int m = rem >> 4, dq = rem & 15;
    int mq = m >> 6, mloc = m & 63;
    float4 s = make_float4(0.f, 0.f, 0.f, 0.f);
#pragma unroll
    for (int c = 0; c < 16; ++c) {
      const float4 v = *reinterpret_cast<const float4*>(
          ws + WS_PART + (((size_t)c * BH_ + bh) * 4 + mq) * 4096 + mloc * 64 + dq * 4);
      s.x += v.x; s.y += v.y; s.z += v.z; s.w += v.w;
    }
    *reinterpret_cast<float4*>(ws + WS_V2X + (size_t)i * 4) = s;
  } else if (i < 131072 + 8192) {
    int j = i - 131072;
    int bh = j >> 8, m = j & 255;
    int mq = m >> 6, mloc = m & 63;
    float s = 0.f;
#pragma unroll
    for (int c = 0; c < 16; ++c)
      s += ws[WS_PSUM + (((size_t)c * BH_ + bh) * 4 + mq) * 64 + mloc];
    ws[WS_V2SUM + j] = s;
  }
}

// ---------------------------------------------------------------- PV + out
// 2048 blocks = bh(32) x tile(64 pos). thread (pg_=t&15, dg=t>>4) owns 4 pos x 4 d.
// 4 m-phases of 64: sA 64x67 (17.2K, 2-way-free reads) + sB 64x68 (17.4K) -> 4 blk/CU.
__global__ __launch_bounds__(256) void k_pv(const float* __restrict__ v1p,
                                            float* __restrict__ ws,
                                            float* __restrict__ out) {
  __shared__ float sA[64][67];
  __shared__ float sB[64][68];
  __shared__ float sVs[256];
  int t = threadIdx.x;
  int bh = blockIdx.x >> 6, tile = blockIdx.x & 63;
  int b = bh >> 3, h = bh & 7;
  int pg_ = t & 15, dg = t >> 4;
  int pl = t >> 2, ps = t & 3;

  if (t < 64) {
    float4 v = *reinterpret_cast<const float4*>(ws + WS_V2SUM + bh * M_ + t * 4);
    *reinterpret_cast<float4*>(&sVs[t * 4]) = v;
  }

  float acc1[4][4];
  float acc2[4];
#pragma unroll
  for (int i = 0; i < 4; ++i) {
    acc2[i] = 0.f;
#pragma unroll
    for (int j = 0; j < 4; ++j) acc1[i][j] = 0.f;
  }

  size_t posg_base = (size_t)(b * N_ + tile * 64) * H_ + h;

  for (int ph = 0; ph < 4; ++ph) {
    __syncthreads();
    int m0 = ph * 64;
    {
      const float* gp = v1p + (posg_base + (size_t)pl * H_) * M_ + m0;
#pragma unroll
      for (int j = 0; j < 4; ++j) {
        int mcol = ps * 4 + j * 16;
        float4 v = *reinterpret_cast<const float4*>(gp + mcol);
        sA[pl][mcol] = v.x; sA[pl][mcol + 1] = v.y;
        sA[pl][mcol + 2] = v.z; sA[pl][mcol + 3] = v.w;
      }
      const float* gb = ws + WS_V2X + (size_t)bh * M_ * D_ + (size_t)(m0 + pl) * 64 + ps * 16;
#pragma unroll
      for (int j = 0; j < 4; ++j) {
        float4 v = *reinterpret_cast<const float4*>(gb + j * 4);
        *reinterpret_cast<float4*>(&sB[pl][ps * 16 + j * 4]) = v;
      }
    }
    __syncthreads();
#pragma unroll 4
    for (int m = 0; m < 64; ++m) {
      float a0 = sA[4 * pg_ + 0][m];
      float a1 = sA[4 * pg_ + 1][m];
      float a2 = sA[4 * pg_ + 2][m];
      float a3 = sA[4 * pg_ + 3][m];
      float4 bv = *reinterpret_cast<const float4*>(&sB[m][dg * 4]);
      float vsm = sVs[m0 + m];
      acc1[0][0] = fmaf(a0, bv.x, acc1[0][0]); acc1[0][1] = fmaf(a0, bv.y, acc1[0][1]);
      acc1[0][2] = fmaf(a0, bv.z, acc1[0][2]); acc1[0][3] = fmaf(a0, bv.w, acc1[0][3]);
      acc1[1][0] = fmaf(a1, bv.x, acc1[1][0]); acc1[1][1] = fmaf(a1, bv.y, acc1[1][1]);
      acc1[1][2] = fmaf(a1, bv.z, acc1[1][2]); acc1[1][3] = fmaf(a1, bv.w, acc1[1][3]);
      acc1[2][0] = fmaf(a2, bv.x, acc1[2][0]); acc1[2][1] = fmaf(a2, bv.y, acc1[2][1]);
      acc1[2][2] = fmaf(a2, bv.z, acc1[2][2]); acc1[2][3] = fmaf(a2, bv.w, acc1[2][3]);
      acc1[3][0] = fmaf(a3, bv.x, acc1[3][0]); acc1[3][1] = fmaf(a3, bv.y, acc1[3][1]);
      acc1[3][2] = fmaf(a3, bv.z, acc1[3][2]); acc1[3][3] = fmaf(a3, bv.w, acc1[3][3]);
      acc2[0] = fmaf(a0, vsm, acc2[0]);
      acc2[1] = fmaf(a1, vsm, acc2[1]);
      acc2[2] = fmaf(a2, vsm, acc2[2]);
      acc2[3] = fmaf(a3, vsm, acc2[3]);
    }
  }

#pragma unroll
  for (int i = 0; i < 4; ++i) {
    size_t pg = posg_base + (size_t)(4 * pg_ + i) * H_;
    float inv = 1.f / acc2[i];
    float4 o;
    o.x = acc1[i][0] * inv; o.y = acc1[i][1] * inv;
    o.z = acc1[i][2] * inv; o.w = acc1[i][3] * inv;
    *reinterpret_cast<float4*>(out + pg * 64 + dg * 4) = o;
  }
}

// ---------------------------------------------------------------- launch
extern "C" void kernel_launch(void* const* d_in, const int* in_sizes, int n_in,
                              void* d_out, int out_size, void* d_ws, size_t ws_size,
                              hipStream_t stream) {
  const float* x  = (const float*)d_in[0];
  const float* v1 = (const float*)d_in[1];
  const float* v2 = (const float*)d_in[2];
  const float* Pm = (const float*)d_in[3];
  float* out = (float*)d_out;
  float* v1p = out + (size_t)POS_ * D_;           // 8388608
  float* v2p = v1p + (size_t)POS_ * M_;           // 41943040
  float* ws = (float*)d_ws;
  int use_part = (ws_size >= (size_t)WS_END * 4) ? 1 : 0;

  k_init<<<1024, 256, 0, stream>>>(ws);
  k_proj<false><<<BH_ * 32, 256, 0, stream>>>(v2, Pm, v2p, ws);  // e2 + bh max
  k_proj<true><<<BH_ * 32, 256, 0, stream>>>(v1, Pm, v1p, ws);   // final v1p
  k_v2accum<<<2048, 256, 0, stream>>>(x, v2p, ws, use_part);     // v2p + partials
  if (use_part) k_reduce<<<544, 256, 0, stream>>>(ws);           // -> v2x, v2sum
  k_pv<<<2048, 256, 0, stream>>>(v1p, ws, out);                  // out
}